// Round 1
// baseline (1400.137 us; speedup 1.0000x reference)
//
#include <hip/hip_runtime.h>
#include <hip/hip_bf16.h>
#include <cstdint>

#define NNODES 100000
#define NEDGES 3200000
#define FDIM   512
#define MPAD   100096   // 782 * 128 (pad M so GEMM has no bounds checks)

typedef __bf16 bf16_t;
typedef __bf16 bf16x8 __attribute__((ext_vector_type(8)));
typedef float  f32x4  __attribute__((ext_vector_type(4)));

static __device__ __forceinline__ bf16x8 ld_frag(const ushort* p) {
    return __builtin_bit_cast(bf16x8, *(const uint4*)p);
}

// ---------------- cast / transpose ----------------

// x fp32 [NNODES,512] -> bf16 [MPAD,512], zero-filled pad rows.
__global__ void cast_x_kernel(const float* __restrict__ x, ushort* __restrict__ xb) {
    size_t t = (size_t)blockIdx.x * 256 + threadIdx.x;   // one thread = 4 elems
    size_t base = t * 4;
    int row = (int)(base >> 9);
    ushort4 pk;
    if (row < NNODES) {
        float4 v = *(const float4*)(x + base);
        pk.x = __builtin_bit_cast(ushort, (bf16_t)v.x);
        pk.y = __builtin_bit_cast(ushort, (bf16_t)v.y);
        pk.z = __builtin_bit_cast(ushort, (bf16_t)v.z);
        pk.w = __builtin_bit_cast(ushort, (bf16_t)v.w);
    } else {
        pk.x = pk.y = pk.z = pk.w = 0;
    }
    *(ushort4*)(xb + base) = pk;
}

// weight fp32 [K=512, N=512] -> wt bf16 [N, K] (transposed, row-major)
__global__ void cast_wt_kernel(const float* __restrict__ w, ushort* __restrict__ wt) {
    int t = blockIdx.x * 256 + threadIdx.x;   // 262144 threads
    int n = t >> 9, k = t & 511;
    wt[(size_t)n * 512 + k] = __builtin_bit_cast(ushort, (bf16_t)w[(size_t)k * 512 + n]);
}

// ---------------- GEMM: support = Xbf @ W  (bf16 in, bf16 out, fp32 acc) ----------------
// 128x128 tile / block of 256 threads; 4 waves each own a 64x64 quadrant (4x4 of 16x16).
// LDS layout [quad][row][8] so each fragment is one aligned 16B ds_read (2-way conflicts only).
__global__ __launch_bounds__(256) void gemm_kernel(const ushort* __restrict__ xb,
                                                   const ushort* __restrict__ wt,
                                                   ushort* __restrict__ sup) {
    __shared__ ushort As[4 * 128 * 8];
    __shared__ ushort Bs[4 * 128 * 8];

    const int tid  = threadIdx.x;
    const int m0   = blockIdx.y * 128;
    const int n0   = blockIdx.x * 128;
    const int wave = tid >> 6, lane = tid & 63;
    const int quad = lane >> 4, r16 = lane & 15;
    const int wm = (wave >> 1) * 64, wn = (wave & 1) * 64;

    // staging assignment: transfer L in [0,512): q = L>>7, row = L&127; this thread does L=tid, L=tid+256
    const int qa = tid >> 7, ra = tid & 127;

    f32x4 acc[4][4];
#pragma unroll
    for (int i = 0; i < 4; ++i)
#pragma unroll
        for (int j = 0; j < 4; ++j) acc[i][j] = f32x4{0.f, 0.f, 0.f, 0.f};

    const size_t arow = (size_t)(m0 + ra) * 512;
    const size_t brow = (size_t)(n0 + ra) * 512;

    for (int kc = 0; kc < 16; ++kc) {
        const int k0 = kc * 32;
        __syncthreads();
        *(uint4*)(As + ((qa    ) * 128 + ra) * 8) = *(const uint4*)(xb + arow + k0 + (qa    ) * 8);
        *(uint4*)(As + ((qa + 2) * 128 + ra) * 8) = *(const uint4*)(xb + arow + k0 + (qa + 2) * 8);
        *(uint4*)(Bs + ((qa    ) * 128 + ra) * 8) = *(const uint4*)(wt + brow + k0 + (qa    ) * 8);
        *(uint4*)(Bs + ((qa + 2) * 128 + ra) * 8) = *(const uint4*)(wt + brow + k0 + (qa + 2) * 8);
        __syncthreads();

        bf16x8 af[4], bfr[4];
#pragma unroll
        for (int i = 0; i < 4; ++i) af[i]  = ld_frag(As + (quad * 128 + wm + 16 * i + r16) * 8);
#pragma unroll
        for (int j = 0; j < 4; ++j) bfr[j] = ld_frag(Bs + (quad * 128 + wn + 16 * j + r16) * 8);

#pragma unroll
        for (int i = 0; i < 4; ++i)
#pragma unroll
            for (int j = 0; j < 4; ++j)
                acc[i][j] = __builtin_amdgcn_mfma_f32_16x16x32_bf16(af[i], bfr[j], acc[i][j], 0, 0, 0);
    }

    // epilogue: C/D layout col=lane&15, row=quad*4+reg
#pragma unroll
    for (int i = 0; i < 4; ++i) {
        const int rowb = m0 + wm + 16 * i + quad * 4;
#pragma unroll
        for (int j = 0; j < 4; ++j) {
            const int col = n0 + wn + 16 * j + r16;
            f32x4 v = acc[i][j];
#pragma unroll
            for (int r = 0; r < 4; ++r)
                sup[(size_t)(rowb + r) * 512 + col] = __builtin_bit_cast(ushort, (bf16_t)v[r]);
        }
    }
}

// ---------------- CSR build ----------------

__global__ void zero_cnt_kernel(int* __restrict__ cnt, int* __restrict__ fill) {
    int i = blockIdx.x * 256 + threadIdx.x;
    if (i < NNODES) { cnt[i] = 0; fill[i] = 0; }
}

__global__ void hist_kernel(const int* __restrict__ ei, int* __restrict__ cnt) {
    int e = blockIdx.x * 256 + threadIdx.x;
    if (e < NEDGES) atomicAdd(&cnt[ei[e]], 1);
}

// single-block exclusive scan over NNODES counts -> row_ptr
__global__ __launch_bounds__(1024) void scan_kernel(const int* __restrict__ cnt, int* __restrict__ ptr) {
    __shared__ int sums[1024];
    const int t = threadIdx.x;
    const int CH = (NNODES + 1023) / 1024;   // 98
    const int b = t * CH;
    const int e = min(b + CH, NNODES);
    int s = 0;
    for (int i = b; i < e; ++i) s += cnt[i];
    sums[t] = s;
    __syncthreads();
    for (int off = 1; off < 1024; off <<= 1) {
        int v = (t >= off) ? sums[t - off] : 0;
        __syncthreads();
        sums[t] += v;
        __syncthreads();
    }
    int run = sums[t] - s;   // exclusive prefix of this chunk
    for (int i = b; i < e; ++i) { ptr[i] = run; run += cnt[i]; }
    if (t == 0) ptr[NNODES] = NEDGES;
}

__global__ void scatter_kernel(const int* __restrict__ ei, const float* __restrict__ ew,
                               const int* __restrict__ ptr, int* __restrict__ fill,
                               int* __restrict__ cols, float* __restrict__ wsrt) {
    int e = blockIdx.x * 256 + threadIdx.x;
    if (e < NEDGES) {
        int r = ei[e];
        int pos = ptr[r] + atomicAdd(&fill[r], 1);
        cols[pos] = ei[NEDGES + e];
        wsrt[pos] = ew[e];
    }
}

// ---------------- SpMM: out[r] = sum_e w_e * sup[col_e] + bias ----------------
// one wave per row; lane covers 8 features (16B bf16 gather, coalesced 1KB/wave/edge)
__global__ __launch_bounds__(256) void spmm_kernel(const ushort* __restrict__ sup,
                                                   const int* __restrict__ ptr,
                                                   const int* __restrict__ cols,
                                                   const float* __restrict__ wsrt,
                                                   const float* __restrict__ bias,
                                                   float* __restrict__ out) {
    const int row  = blockIdx.x * 4 + (threadIdx.x >> 6);
    const int lane = threadIdx.x & 63;
    const int fo   = lane * 8;
    const int start = ptr[row], end = ptr[row + 1];

    float acc[8];
#pragma unroll
    for (int j = 0; j < 8; ++j) acc[j] = 0.f;

    for (int i = start; i < end; ++i) {
        const int c = cols[i];
        const float w = wsrt[i];
        bf16x8 sv = __builtin_bit_cast(bf16x8, *(const uint4*)(sup + (size_t)c * 512 + fo));
#pragma unroll
        for (int j = 0; j < 8; ++j) acc[j] += w * (float)sv[j];
    }

    const float4 b0 = *(const float4*)(bias + fo);
    const float4 b1 = *(const float4*)(bias + fo + 4);
    float* op = out + (size_t)row * 512 + fo;
    *(float4*)(op)     = make_float4(acc[0] + b0.x, acc[1] + b0.y, acc[2] + b0.z, acc[3] + b0.w);
    *(float4*)(op + 4) = make_float4(acc[4] + b1.x, acc[5] + b1.y, acc[6] + b1.z, acc[7] + b1.w);
}

// ---------------- launch ----------------

extern "C" void kernel_launch(void* const* d_in, const int* in_sizes, int n_in,
                              void* d_out, int out_size, void* d_ws, size_t ws_size,
                              hipStream_t stream) {
    const float* x    = (const float*)d_in[0];
    const int*   ei   = (const int*)d_in[1];     // [2, E]
    const float* ew   = (const float*)d_in[2];
    const float* w    = (const float*)d_in[3];
    const float* bias = (const float*)d_in[4];
    float* out = (float*)d_out;

    char* ws = (char*)d_ws;
    size_t off = 0;
    auto take = [&](size_t bytes) { char* p = ws + off; off = (off + bytes + 255) & ~(size_t)255; return p; };

    ushort* xb   = (ushort*)take((size_t)MPAD * FDIM * 2);   // 102.5 MB
    ushort* sup  = (ushort*)take((size_t)MPAD * FDIM * 2);   // 102.5 MB
    ushort* wt   = (ushort*)take((size_t)FDIM * FDIM * 2);   // 0.5 MB
    int*   cnt   = (int*)take((size_t)NNODES * 4);
    int*   ptr   = (int*)take((size_t)(NNODES + 1) * 4);
    int*   fill  = (int*)take((size_t)NNODES * 4);
    int*   cols  = (int*)take((size_t)NEDGES * 4);           // 12.8 MB
    float* wsrt  = (float*)take((size_t)NEDGES * 4);         // 12.8 MB

    hipLaunchKernelGGL(cast_x_kernel, dim3((MPAD * FDIM / 4) / 256), dim3(256), 0, stream, x, xb);
    hipLaunchKernelGGL(cast_wt_kernel, dim3(1024), dim3(256), 0, stream, w, wt);
    hipLaunchKernelGGL(gemm_kernel, dim3(FDIM / 128, MPAD / 128), dim3(256), 0, stream, xb, wt, sup);
    hipLaunchKernelGGL(zero_cnt_kernel, dim3((NNODES + 255) / 256), dim3(256), 0, stream, cnt, fill);
    hipLaunchKernelGGL(hist_kernel, dim3(NEDGES / 256), dim3(256), 0, stream, ei, cnt);
    hipLaunchKernelGGL(scan_kernel, dim3(1), dim3(1024), 0, stream, cnt, ptr);
    hipLaunchKernelGGL(scatter_kernel, dim3(NEDGES / 256), dim3(256), 0, stream, ei, ew, ptr, fill, cols, wsrt);
    hipLaunchKernelGGL(spmm_kernel, dim3(NNODES / 4), dim3(256), 0, stream, sup, ptr, cols, wsrt, bias, out);
}